// Round 1
// baseline (165.664 us; speedup 1.0000x reference)
//
#include <hip/hip_runtime.h>
#include <hip/hip_bf16.h>

#define NB 4
#define SS 1024
#define DIN 768
#define NH 12
#define DH 64

typedef float f32x4 __attribute__((ext_vector_type(4)));
typedef short bf16x8 __attribute__((ext_vector_type(8)));

static __device__ __forceinline__ unsigned short f2bf(float f) {
    __hip_bfloat16 h = __float2bfloat16(f);
    return *reinterpret_cast<unsigned short*>(&h);
}

// ---------------- kernel 1: cast x (f32) -> xb (bf16), [4096][768] ----------------
__global__ void cast_x_kernel(const float* __restrict__ x, unsigned short* __restrict__ xb) {
    int i = (blockIdx.x * 256 + threadIdx.x) * 4;
    float4 v = *reinterpret_cast<const float4*>(x + i);
    ushort4 o;
    o.x = f2bf(v.x); o.y = f2bf(v.y); o.z = f2bf(v.z); o.w = f2bf(v.w);
    *reinterpret_cast<ushort4*>(xb + i) = o;
}

// ------------- kernel 2: W [H][DIN][DH] f32 -> wt [3][H][DH][DIN] bf16 -------------
__global__ void transpose_w_kernel(const float* __restrict__ Wq, const float* __restrict__ Wk,
                                   const float* __restrict__ Wv, unsigned short* __restrict__ wt) {
    __shared__ float lds[64][68];
    int d0 = blockIdx.x * 64;
    int h  = blockIdx.y;
    int p  = blockIdx.z;
    const float* W = (p == 0) ? Wq : (p == 1) ? Wk : Wv;
    const float* base = W + (size_t)h * DIN * DH;   // [768][64]
    int tid = threadIdx.x;
    int rr = tid >> 4, c4 = tid & 15;
#pragma unroll
    for (int i = 0; i < 4; ++i) {
        int d = i * 16 + rr;
        float4 v = *reinterpret_cast<const float4*>(base + (size_t)(d0 + d) * DH + c4 * 4);
        lds[d][c4 * 4 + 0] = v.x; lds[d][c4 * 4 + 1] = v.y;
        lds[d][c4 * 4 + 2] = v.z; lds[d][c4 * 4 + 3] = v.w;
    }
    __syncthreads();
    unsigned short* outp = wt + ((size_t)(p * NH + h) * DH) * DIN;
#pragma unroll
    for (int i = 0; i < 4; ++i) {
        int e = i * 16 + rr;
        int dc = c4 * 4;
        ushort4 o;
        o.x = f2bf(lds[dc + 0][e]); o.y = f2bf(lds[dc + 1][e]);
        o.z = f2bf(lds[dc + 2][e]); o.w = f2bf(lds[dc + 3][e]);
        *reinterpret_cast<ushort4*>(outp + (size_t)e * DIN + d0 + dc) = o;
    }
}

// ---- kernel 3: fused QKV GEMM. block = (64-row m-tile, head). out: q,k [b][h][t][e] bf16,
// ----           v transposed  [b][h][e][t] bf16. 256 thr = 4 waves, each wave 16 rows.
__global__ void qkv_gemm_kernel(const unsigned short* __restrict__ xb,
                                const unsigned short* __restrict__ wt,
                                unsigned short* __restrict__ qb,
                                unsigned short* __restrict__ kb,
                                unsigned short* __restrict__ vT) {
    __shared__ __align__(16) unsigned char smem[36864];
    unsigned short* a_lds = (unsigned short*)smem;            // [64][72] bf16
    unsigned short* b_lds = (unsigned short*)(smem + 9216);   // [3][64][72] bf16
    float*          v_lds = (float*)smem;                     // [64][68] f32 (aliases, epilogue only)

    int m0 = blockIdx.x * 64;
    int h  = blockIdx.y;
    int tid = threadIdx.x;
    int lane = tid & 63, w = tid >> 6;
    int l15 = lane & 15, hi4 = (lane >> 4) * 4, hi8 = (lane >> 4) * 8;

    f32x4 acc[3][4] = {};

    int seg = tid * 2;
    int srow = seg >> 3, sc = (seg & 7) * 8;   // row 0..63, col offset {0,16,32,48}

    for (int k0 = 0; k0 < DIN; k0 += 64) {
        // stage A tile (xb rows m0..m0+63, cols k0..k0+63)
        {
            const uint4* g = reinterpret_cast<const uint4*>(xb + (size_t)(m0 + srow) * DIN + k0 + sc);
            *reinterpret_cast<uint4*>(a_lds + srow * 72 + sc)     = g[0];
            *reinterpret_cast<uint4*>(a_lds + srow * 72 + sc + 8) = g[1];
        }
        // stage B tiles for q,k,v (wt rows = e, cols = d)
#pragma unroll
        for (int p = 0; p < 3; ++p) {
            const uint4* g = reinterpret_cast<const uint4*>(
                wt + (size_t)(p * NH + h) * DH * DIN + (size_t)srow * DIN + k0 + sc);
            *reinterpret_cast<uint4*>(b_lds + p * 4608 + srow * 72 + sc)     = g[0];
            *reinterpret_cast<uint4*>(b_lds + p * 4608 + srow * 72 + sc + 8) = g[1];
        }
        __syncthreads();
#pragma unroll
        for (int s = 0; s < 2; ++s) {
            bf16x8 af = *reinterpret_cast<const bf16x8*>(a_lds + (16 * w + l15) * 72 + 32 * s + hi8);
#pragma unroll
            for (int p = 0; p < 3; ++p)
#pragma unroll
                for (int n = 0; n < 4; ++n) {
                    bf16x8 bfrag = *reinterpret_cast<const bf16x8*>(
                        b_lds + p * 4608 + (16 * n + l15) * 72 + 32 * s + hi8);
                    acc[p][n] = __builtin_amdgcn_mfma_f32_16x16x32_bf16(af, bfrag, acc[p][n], 0, 0, 0);
                }
        }
        __syncthreads();
    }

    int b = m0 >> 10;
    int s_base = m0 & 1023;
    // Q and K: direct bf16 stores [b][h][t][e]
#pragma unroll
    for (int pq = 0; pq < 2; ++pq) {
        unsigned short* dst = (pq == 0 ? qb : kb) + ((size_t)(b * NH + h) * SS + s_base) * DH;
#pragma unroll
        for (int n = 0; n < 4; ++n)
#pragma unroll
            for (int r = 0; r < 4; ++r) {
                int t = 16 * w + hi4 + r;
                int e = 16 * n + l15;
                dst[(size_t)t * DH + e] = f2bf(acc[pq][n][r]);
            }
    }
    // V: transpose through LDS, store [b][h][e][t]
#pragma unroll
    for (int n = 0; n < 4; ++n)
#pragma unroll
        for (int r = 0; r < 4; ++r) {
            int t = 16 * w + hi4 + r;
            int e = 16 * n + l15;
            v_lds[t * 68 + e] = acc[2][n][r];
        }
    __syncthreads();
    {
        int e = tid >> 2, tch = (tid & 3) * 16;
        unsigned short vals[16];
#pragma unroll
        for (int t = 0; t < 16; ++t) vals[t] = f2bf(v_lds[(tch + t) * 68 + e]);
        unsigned short* dst = vT + ((size_t)(b * NH + h) * DH + e) * SS + s_base + tch;
        *reinterpret_cast<uint4*>(dst)     = *reinterpret_cast<const uint4*>(vals);
        *reinterpret_cast<uint4*>(dst + 8) = *reinterpret_cast<const uint4*>(vals + 8);
    }
}

// ---- kernel 4: causal flash attention. block = (q-tile 64, h, b), 4 waves x 16 q-rows.
__global__ void attn_kernel(const unsigned short* __restrict__ qb,
                            const unsigned short* __restrict__ kb,
                            const unsigned short* __restrict__ vT,
                            float* __restrict__ out) {
    __shared__ __align__(16) unsigned short k_lds[64 * 72];       // [t][e] padded
    __shared__ __align__(16) unsigned short v_lds[64 * 72];       // [e][t] padded
    __shared__ __align__(16) unsigned short p_lds[4 * 16 * 72];   // per-wave [16 q][64 t] padded

    int qi = blockIdx.x;
    int h  = blockIdx.y;
    int b  = blockIdx.z;
    int q0 = qi * 64;
    int tid = threadIdx.x, lane = tid & 63, w = tid >> 6;
    int l15 = lane & 15, hi4 = (lane >> 4) * 4, hi8 = (lane >> 4) * 8;
    size_t bh = (size_t)(b * NH + h);

    // Q fragments live in registers for the whole kernel
    const unsigned short* qp = qb + (bh * SS + q0 + 16 * w + l15) * DH;
    bf16x8 qf[2];
    qf[0] = *reinterpret_cast<const bf16x8*>(qp + hi8);
    qf[1] = *reinterpret_cast<const bf16x8*>(qp + 32 + hi8);

    float m_r[4], l_r[4];
    f32x4 o_acc[4] = {};
#pragma unroll
    for (int r = 0; r < 4; ++r) { m_r[r] = -INFINITY; l_r[r] = 0.f; }

    int seg = tid * 2;
    int srow = seg >> 3, sc = (seg & 7) * 8;
    const unsigned short* kg = kb + bh * SS * DH;
    const unsigned short* vg = vT + bh * DH * SS;

    for (int kv = 0; kv <= qi; ++kv) {
        // stage K [64 t][64 e] and V^T [64 e][64 t]
        {
            const uint4* g0 = reinterpret_cast<const uint4*>(kg + (size_t)(kv * 64 + srow) * DH + sc);
            *reinterpret_cast<uint4*>(k_lds + srow * 72 + sc)     = g0[0];
            *reinterpret_cast<uint4*>(k_lds + srow * 72 + sc + 8) = g0[1];
            const uint4* g1 = reinterpret_cast<const uint4*>(vg + (size_t)srow * SS + kv * 64 + sc);
            *reinterpret_cast<uint4*>(v_lds + srow * 72 + sc)     = g1[0];
            *reinterpret_cast<uint4*>(v_lds + srow * 72 + sc + 8) = g1[1];
        }
        __syncthreads();

        // scores = Q . K^T  (A rows = wave's 16 q, B cols = 64 t)
        f32x4 sacc[4] = {};
#pragma unroll
        for (int s = 0; s < 2; ++s)
#pragma unroll
            for (int n = 0; n < 4; ++n) {
                bf16x8 kf = *reinterpret_cast<const bf16x8*>(k_lds + (16 * n + l15) * 72 + 32 * s + hi8);
                sacc[n] = __builtin_amdgcn_mfma_f32_16x16x32_bf16(qf[s], kf, sacc[n], 0, 0, 0);
            }

        bool diag = (kv == qi);
        float pv[4][4];
#pragma unroll
        for (int n = 0; n < 4; ++n)
#pragma unroll
            for (int r = 0; r < 4; ++r) {
                float sv = sacc[n][r] * 0.125f;   // 1/sqrt(64)
                if (diag && (kv * 64 + 16 * n + l15) > (q0 + 16 * w + hi4 + r)) sv = -INFINITY;
                pv[n][r] = sv;
            }

        // online softmax, per owned row r (reduce across the 16 lanes of the row group)
#pragma unroll
        for (int r = 0; r < 4; ++r) {
            float mx = fmaxf(fmaxf(pv[0][r], pv[1][r]), fmaxf(pv[2][r], pv[3][r]));
#pragma unroll
            for (int d = 1; d < 16; d <<= 1) mx = fmaxf(mx, __shfl_xor(mx, d));
            float m_new = fmaxf(m_r[r], mx);
            float sum = 0.f;
#pragma unroll
            for (int n = 0; n < 4; ++n) {
                float e = __expf(pv[n][r] - m_new);
                pv[n][r] = e;
                sum += e;
            }
#pragma unroll
            for (int d = 1; d < 16; d <<= 1) sum += __shfl_xor(sum, d);
            float alpha = __expf(m_r[r] - m_new);
            l_r[r] = l_r[r] * alpha + sum;
            m_r[r] = m_new;
#pragma unroll
            for (int n = 0; n < 4; ++n) o_acc[n][r] *= alpha;
        }

        // P -> bf16 -> per-wave LDS (C/D layout -> A-frag layout round trip)
        unsigned short* pw = p_lds + w * 16 * 72;
#pragma unroll
        for (int n = 0; n < 4; ++n)
#pragma unroll
            for (int r = 0; r < 4; ++r)
                pw[(hi4 + r) * 72 + 16 * n + l15] = f2bf(pv[n][r]);
        __syncthreads();

        // O += P . V   (B-frag from V^T tile: col=e, k=t contiguous)
        bf16x8 pa[2];
        pa[0] = *reinterpret_cast<const bf16x8*>(pw + l15 * 72 + hi8);
        pa[1] = *reinterpret_cast<const bf16x8*>(pw + l15 * 72 + 32 + hi8);
#pragma unroll
        for (int s = 0; s < 2; ++s)
#pragma unroll
            for (int n = 0; n < 4; ++n) {
                bf16x8 vf = *reinterpret_cast<const bf16x8*>(v_lds + (16 * n + l15) * 72 + 32 * s + hi8);
                o_acc[n] = __builtin_amdgcn_mfma_f32_16x16x32_bf16(pa[s], vf, o_acc[n], 0, 0, 0);
            }
        __syncthreads();
    }

    float inv[4];
#pragma unroll
    for (int r = 0; r < 4; ++r) inv[r] = 1.f / l_r[r];
#pragma unroll
    for (int n = 0; n < 4; ++n)
#pragma unroll
        for (int r = 0; r < 4; ++r) {
            int q = q0 + 16 * w + hi4 + r;
            int e = 16 * n + l15;
            out[((size_t)b * SS + q) * (NH * DH) + h * DH + e] = o_acc[n][r] * inv[r];
        }
}

extern "C" void kernel_launch(void* const* d_in, const int* in_sizes, int n_in,
                              void* d_out, int out_size, void* d_ws, size_t ws_size,
                              hipStream_t stream) {
    const float* x  = (const float*)d_in[0];
    const float* Wq = (const float*)d_in[1];
    const float* Wk = (const float*)d_in[2];
    const float* Wv = (const float*)d_in[3];
    float* out = (float*)d_out;

    char* ws = (char*)d_ws;
    unsigned short* xb = (unsigned short*)ws;                   //  6,291,456 B
    unsigned short* wt = (unsigned short*)(ws +  6291456);      //  3,538,944 B
    unsigned short* qb = (unsigned short*)(ws +  9830400);      //  6,291,456 B
    unsigned short* kb = (unsigned short*)(ws + 16121856);      //  6,291,456 B
    unsigned short* vT = (unsigned short*)(ws + 22413312);      //  6,291,456 B (ends 28,704,768)

    hipLaunchKernelGGL(cast_x_kernel,     dim3(3072),      dim3(256), 0, stream, x, xb);
    hipLaunchKernelGGL(transpose_w_kernel,dim3(12, 12, 3), dim3(256), 0, stream, Wq, Wk, Wv, wt);
    hipLaunchKernelGGL(qkv_gemm_kernel,   dim3(64, 12),    dim3(256), 0, stream, xb, wt, qb, kb, vT);
    hipLaunchKernelGGL(attn_kernel,       dim3(16, 12, 4), dim3(256), 0, stream, qb, kb, vT, out);
}